// Round 4
// baseline (220.384 us; speedup 1.0000x reference)
//
#include <hip/hip_runtime.h>

// LGAN layer on a fixed 8-ring graph, N=20000, D=128, MH=256.
// R3: fully register-resident MLPs — no LDS, no barriers.
//   Each wave owns 16 rows x all 256 mid-cols; stage1 MFMA D-quads are
//   relu'd + cvt'd in-register and concatenated into stage2 B-frags via a
//   k-permutation sigma baked into the stage-2 weight layout:
//     slot s = 32kk+8lg+j  holds logical k = 32kk + 16*(j>>2) + 4lg + (j&3)
//   (W2-style weights stored pre-permuted by cvt_weights).

#define NN 20000
#define NE 160000
#define DD 128
#define MHD 256

typedef __attribute__((ext_vector_type(8))) short short8;
typedef __attribute__((ext_vector_type(4))) short short4v;
typedef __attribute__((ext_vector_type(4))) float f32x4;

__device__ __forceinline__ float bf2f(short s) {
  return __builtin_bit_cast(float, (unsigned int)((unsigned short)s) << 16);
}
__device__ __forceinline__ short f2bf(float f) {
  unsigned int u = __builtin_bit_cast(unsigned int, f);
  u = (u + 0x7FFFu + ((u >> 16) & 1u)) >> 16;
  return (short)u;
}

#define MFMA(a, b, c) __builtin_amdgcn_mfma_f32_16x16x32_bf16((a), (b), (c), 0, 0, 0)

// ---- Kernel A: h_e = MLP_e(h[u] + h[v]); 128 edges/block, 32/wave ----
__global__ __launch_bounds__(256) void edge_mlp(
    const short* __restrict__ hbf, const short* __restrict__ We1t,
    const float* __restrict__ be1, const short* __restrict__ We2tP,
    const float* __restrict__ be2, short* __restrict__ he) {
  const int t = threadIdx.x;
  const int lane = t & 63, w = t >> 6;
  const int lr = lane & 15, lg = lane >> 4;
  const int ebase = blockIdx.x * 128 + w * 32;

  // X-frags: X = bf16(h[u]+h[v]); lane (lr,lg) holds row lr of its rowset,
  // k = 32kk + 8lg + (0..7).
  short8 xf[2][4];
#pragma unroll
  for (int rs = 0; rs < 2; ++rs) {
    const int e = ebase + rs * 16 + lr;
    const int j = e / NN + 1;
    const int i = e - (j - 1) * NN;
    int v = i + j;
    if (v >= NN) v -= NN;
    const short* hu = hbf + (size_t)i * DD;
    const short* hv = hbf + (size_t)v * DD;
#pragma unroll
    for (int kk = 0; kk < 4; ++kk) {
      short8 a = *(const short8*)&hu[kk * 32 + lg * 8];
      short8 b = *(const short8*)&hv[kk * 32 + lg * 8];
      short8 z;
#pragma unroll
      for (int q = 0; q < 8; ++q) z[q] = f2bf(bf2f(a[q]) + bf2f(b[q]));
      xf[rs][kk] = z;
    }
  }

  // Stage 1: 16 col-tiles of the 256 mid dims; D-quads -> h1b halves.
  short8 h1b[2][8];
#pragma unroll
  for (int ct = 0; ct < 16; ++ct) {
    short8 aw[4];
#pragma unroll
    for (int kk = 0; kk < 4; ++kk)
      aw[kk] = *(const short8*)&We1t[(ct * 16 + lr) * 128 + kk * 32 + lg * 8];
    const f32x4 bias = *(const f32x4*)&be1[ct * 16 + 4 * lg];
#pragma unroll
    for (int rs = 0; rs < 2; ++rs) {
      f32x4 acc = bias;
#pragma unroll
      for (int kk = 0; kk < 4; ++kk) acc = MFMA(aw[kk], xf[rs][kk], acc);
#pragma unroll
      for (int q = 0; q < 4; ++q) {
        float x = acc[q] > 0.f ? acc[q] : 0.f;
        h1b[rs][ct >> 1][(ct & 1) * 4 + q] = f2bf(x);
      }
    }
  }

  // Stage 2: 8 out col-tiles; A from sigma-permuted W2.
#pragma unroll
  for (int ct2 = 0; ct2 < 8; ++ct2) {
    short8 aw2[8];
#pragma unroll
    for (int kk = 0; kk < 8; ++kk)
      aw2[kk] = *(const short8*)&We2tP[(ct2 * 16 + lr) * 256 + kk * 32 + lg * 8];
    const f32x4 bias = *(const f32x4*)&be2[ct2 * 16 + 4 * lg];
#pragma unroll
    for (int rs = 0; rs < 2; ++rs) {
      f32x4 acc = bias;
#pragma unroll
      for (int kk = 0; kk < 8; ++kk) acc = MFMA(aw2[kk], h1b[rs][kk], acc);
      short4v o;
#pragma unroll
      for (int q = 0; q < 4; ++q) o[q] = f2bf(acc[q]);
      const int row = ebase + rs * 16 + lr;
      *(short4v*)&he[(size_t)row * DD + ct2 * 16 + 4 * lg] = o;
    }
  }
}

// ---- Kernel B: stencil aggregation -> cat[v][0:128]=aggr_t, [128:256]=aggr_n ----
__global__ __launch_bounds__(256) void aggregate(const short* __restrict__ he,
                                                 short* __restrict__ catb) {
  const int t = threadIdx.x;
  const int v = blockIdx.x * 16 + (t >> 4);
  const int d0 = (t & 15) * 8;
  float at[8], an[8];
#pragma unroll
  for (int q = 0; q < 8; ++q) {
    at[q] = 0.f;
    an[q] = 0.f;
  }
#pragma unroll
  for (int j = 0; j < 8; ++j) {
    const int jj = j + 1;
    const short* base = he + (size_t)j * NN * DD;
    {
      int r2 = v - jj;
      if (r2 < 0) r2 += NN;
      short8 x = *(const short8*)&base[(size_t)v * DD + d0];
      short8 y = *(const short8*)&base[(size_t)r2 * DD + d0];
#pragma unroll
      for (int q = 0; q < 8; ++q) at[q] += bf2f(x[q]) + bf2f(y[q]);
    }
#pragma unroll
    for (int o = jj - 8; o <= 8; ++o) {
      if (o == 0 || o == jj) continue;
      int r = v - o;
      if (r < 0) r += NN;
      else if (r >= NN) r -= NN;
      short8 x = *(const short8*)&base[(size_t)r * DD + d0];
#pragma unroll
      for (int q = 0; q < 8; ++q) an[q] += bf2f(x[q]);
    }
  }
  short8 o1, o2;
#pragma unroll
  for (int q = 0; q < 8; ++q) {
    o1[q] = f2bf(at[q]);
    o2[q] = f2bf(an[q]);
  }
  *(short8*)&catb[(size_t)v * 256 + d0] = o1;
  *(short8*)&catb[(size_t)v * 256 + 128 + d0] = o2;
}

// ---- Kernel C: t = MLP_f(cat) + h @ W_r + b_r; 64 rows/block, 16/wave ----
__global__ __launch_bounds__(256) void fuse_mlp(
    const short* __restrict__ catb, const short* __restrict__ hbf,
    const short* __restrict__ Wf1t, const float* __restrict__ bf1,
    const short* __restrict__ Wf2tP, const float* __restrict__ bf2_,
    const short* __restrict__ Wrt, const float* __restrict__ br,
    short* __restrict__ tout) {
  const int t = threadIdx.x;
  const int lane = t & 63, w = t >> 6;
  const int lr = lane & 15, lg = lane >> 4;
  const int vrow = blockIdx.x * 64 + w * 16 + lr;
  const int rc = vrow < NN ? vrow : NN - 1;  // clamp loads; stores guarded

  short8 xf[8];
#pragma unroll
  for (int kk = 0; kk < 8; ++kk)
    xf[kk] = *(const short8*)&catb[(size_t)rc * 256 + kk * 32 + lg * 8];
  short8 xh[4];
#pragma unroll
  for (int kk = 0; kk < 4; ++kk)
    xh[kk] = *(const short8*)&hbf[(size_t)rc * DD + kk * 32 + lg * 8];

  short8 h1b[8];
#pragma unroll
  for (int ct = 0; ct < 16; ++ct) {
    short8 aw[8];
#pragma unroll
    for (int kk = 0; kk < 8; ++kk)
      aw[kk] = *(const short8*)&Wf1t[(ct * 16 + lr) * 256 + kk * 32 + lg * 8];
    const f32x4 bias = *(const f32x4*)&bf1[ct * 16 + 4 * lg];
    f32x4 acc = bias;
#pragma unroll
    for (int kk = 0; kk < 8; ++kk) acc = MFMA(aw[kk], xf[kk], acc);
#pragma unroll
    for (int q = 0; q < 4; ++q) {
      float x = acc[q] > 0.f ? acc[q] : 0.f;
      h1b[ct >> 1][(ct & 1) * 4 + q] = f2bf(x);
    }
  }

#pragma unroll
  for (int ct2 = 0; ct2 < 8; ++ct2) {
    f32x4 acc;
    {
      const f32x4 b0 = *(const f32x4*)&br[ct2 * 16 + 4 * lg];
      const f32x4 b1 = *(const f32x4*)&bf2_[ct2 * 16 + 4 * lg];
      acc = b0 + b1;
    }
#pragma unroll
    for (int kk = 0; kk < 8; ++kk) {
      short8 aw2 = *(const short8*)&Wf2tP[(ct2 * 16 + lr) * 256 + kk * 32 + lg * 8];
      acc = MFMA(aw2, h1b[kk], acc);
    }
#pragma unroll
    for (int kk = 0; kk < 4; ++kk) {
      short8 awr = *(const short8*)&Wrt[(ct2 * 16 + lr) * 128 + kk * 32 + lg * 8];
      acc = MFMA(awr, xh[kk], acc);
    }
    if (vrow < NN) {
      short4v o;
#pragma unroll
      for (int q = 0; q < 4; ++q) o[q] = f2bf(acc[q]);
      *(short4v*)&tout[(size_t)vrow * DD + ct2 * 16 + 4 * lg] = o;
    }
  }
}

// ---- Kernel D: out = MLP_p(t), fp32 output; 64 rows/block ----
__global__ __launch_bounds__(256) void out_mlp(
    const short* __restrict__ tin, const short* __restrict__ Wp1t,
    const float* __restrict__ bp1, const short* __restrict__ Wp2tP,
    const float* __restrict__ bp2, float* __restrict__ out) {
  const int t = threadIdx.x;
  const int lane = t & 63, w = t >> 6;
  const int lr = lane & 15, lg = lane >> 4;
  const int vrow = blockIdx.x * 64 + w * 16 + lr;
  const int rc = vrow < NN ? vrow : NN - 1;

  short8 xf[4];
#pragma unroll
  for (int kk = 0; kk < 4; ++kk)
    xf[kk] = *(const short8*)&tin[(size_t)rc * DD + kk * 32 + lg * 8];

  short8 h1b[8];
#pragma unroll
  for (int ct = 0; ct < 16; ++ct) {
    short8 aw[4];
#pragma unroll
    for (int kk = 0; kk < 4; ++kk)
      aw[kk] = *(const short8*)&Wp1t[(ct * 16 + lr) * 128 + kk * 32 + lg * 8];
    const f32x4 bias = *(const f32x4*)&bp1[ct * 16 + 4 * lg];
    f32x4 acc = bias;
#pragma unroll
    for (int kk = 0; kk < 4; ++kk) acc = MFMA(aw[kk], xf[kk], acc);
#pragma unroll
    for (int q = 0; q < 4; ++q) {
      float x = acc[q] > 0.f ? acc[q] : 0.f;
      h1b[ct >> 1][(ct & 1) * 4 + q] = f2bf(x);
    }
  }

#pragma unroll
  for (int ct2 = 0; ct2 < 8; ++ct2) {
    f32x4 acc = *(const f32x4*)&bp2[ct2 * 16 + 4 * lg];
#pragma unroll
    for (int kk = 0; kk < 8; ++kk) {
      short8 aw2 = *(const short8*)&Wp2tP[(ct2 * 16 + lr) * 256 + kk * 32 + lg * 8];
      acc = MFMA(aw2, h1b[kk], acc);
    }
    if (vrow < NN)
      *(f32x4*)&out[(size_t)vrow * DD + ct2 * 16 + 4 * lg] = acc;
  }
}

// ---- conversions ----
__global__ __launch_bounds__(256) void cvt_h(const float* __restrict__ src,
                                             short* __restrict__ dst) {
  const size_t id = (size_t)(blockIdx.x * 256 + threadIdx.x) * 8;
  float4 a = *(const float4*)&src[id];
  float4 b = *(const float4*)&src[id + 4];
  short8 o;
  o[0] = f2bf(a.x); o[1] = f2bf(a.y); o[2] = f2bf(a.z); o[3] = f2bf(a.w);
  o[4] = f2bf(b.x); o[5] = f2bf(b.y); o[6] = f2bf(b.z); o[7] = f2bf(b.w);
  *(short8*)&dst[id] = o;
}

// sigma: slot s -> logical k (for W2-style [M][256] permuted storage)
__device__ __forceinline__ int klog_of_slot(int s) {
  return ((s >> 5) << 5) + (((s >> 2) & 1) << 4) + (((s >> 3) & 3) << 2) + (s & 3);
}

// pool: We1t[32768] We2tP[32768] Wf1t[65536] Wf2tP[32768] Wrt[16384]
//       Wp1t[32768] Wp2tP[32768]; first-layer weights [M][K] k-contig,
//       second-layer weights [M][256] sigma-permuted (Wrt natural [M][128]).
__global__ __launch_bounds__(256) void cvt_weights(
    const float* __restrict__ We1, const float* __restrict__ We2,
    const float* __restrict__ Wf1, const float* __restrict__ Wf2,
    const float* __restrict__ Wr, const float* __restrict__ Wp1,
    const float* __restrict__ Wp2, short* __restrict__ dst) {
  const int id = blockIdx.x * 256 + threadIdx.x;
  float v;
  if (id < 32768) {                       // We1t [256][128]
    const int l = id;
    v = We1[(l & 127) * 256 + (l >> 7)];
  } else if (id < 65536) {                // We2tP [128][256]
    const int l = id - 32768;
    v = We2[klog_of_slot(l & 255) * 128 + (l >> 8)];
  } else if (id < 131072) {               // Wf1t [256][256]
    const int l = id - 65536;
    v = Wf1[(l & 255) * 256 + (l >> 8)];
  } else if (id < 163840) {               // Wf2tP [128][256]
    const int l = id - 131072;
    v = Wf2[klog_of_slot(l & 255) * 128 + (l >> 8)];
  } else if (id < 180224) {               // Wrt [128][128] natural
    const int l = id - 163840;
    v = Wr[(l & 127) * 128 + (l >> 7)];
  } else if (id < 212992) {               // Wp1t [256][128]
    const int l = id - 180224;
    v = Wp1[(l & 127) * 256 + (l >> 7)];
  } else {                                // Wp2tP [128][256]
    const int l = id - 212992;
    v = Wp2[klog_of_slot(l & 255) * 128 + (l >> 8)];
  }
  dst[id] = f2bf(v);
}

extern "C" void kernel_launch(void* const* d_in, const int* in_sizes, int n_in,
                              void* d_out, int out_size, void* d_ws,
                              size_t ws_size, hipStream_t stream) {
  const float* h = (const float*)d_in[0];
  const float* We1 = (const float*)d_in[4];
  const float* be1 = (const float*)d_in[5];
  const float* We2 = (const float*)d_in[6];
  const float* be2 = (const float*)d_in[7];
  const float* Wf1 = (const float*)d_in[8];
  const float* bf1 = (const float*)d_in[9];
  const float* Wf2 = (const float*)d_in[10];
  const float* bf2 = (const float*)d_in[11];
  const float* Wr = (const float*)d_in[12];
  const float* br = (const float*)d_in[13];
  const float* Wp1 = (const float*)d_in[14];
  const float* bp1 = (const float*)d_in[15];
  const float* Wp2 = (const float*)d_in[16];
  const float* bp2 = (const float*)d_in[17];

  char* ws = (char*)d_ws;
  short* hbf = (short*)ws;                      // 20000*128*2   = 5,120,000
  short* he = (short*)(ws + 5120000);           // 160000*128*2  = 40,960,000
  short* catb = (short*)(ws + 46080000);        // 20000*256*2   = 10,240,000
  short* tbuf = (short*)(ws + 56320000);        // 20000*128*2   = 5,120,000
  short* wpool = (short*)(ws + 61440000);       // 245760*2      = 491,520
  short* We1t = wpool;
  short* We2tP = We1t + 32768;
  short* Wf1t = We2tP + 32768;
  short* Wf2tP = Wf1t + 65536;
  short* Wrt = Wf2tP + 32768;
  short* Wp1t = Wrt + 16384;
  short* Wp2tP = Wp1t + 32768;

  cvt_h<<<1250, 256, 0, stream>>>(h, hbf);
  cvt_weights<<<960, 256, 0, stream>>>(We1, We2, Wf1, Wf2, Wr, Wp1, Wp2, wpool);
  edge_mlp<<<NE / 128, 256, 0, stream>>>(hbf, We1t, be1, We2tP, be2, he);
  aggregate<<<NN / 16, 256, 0, stream>>>(he, catb);
  fuse_mlp<<<(NN + 63) / 64, 256, 0, stream>>>(catb, hbf, Wf1t, bf1, Wf2tP, bf2,
                                               Wrt, br, tbuf);
  out_mlp<<<(NN + 63) / 64, 256, 0, stream>>>(tbuf, Wp1t, bp1, Wp2tP, bp2,
                                              (float*)d_out);
}